// Round 11
// baseline (276.775 us; speedup 1.0000x reference)
//
#include <hip/hip_runtime.h>

// ---------------------------------------------------------------------------
// TransformerBlock: B=2,S=2048,D=768,H=12,DH=64,DFF=3072, causal attn, 2x LN
// Round 24: FFN2 -> 8-phase gemm256 with split-K=4. R23 top-5 = harness
// workspace fill (256MB alloc revealed -> layout pressure gone; fill is
// constant, not ours). FFN2-n64 was the biggest remaining GEMM (~30us @16%
// MfmaUtil, the 2-phase structural cap). gemm256 mode2: grid (3,16,4) = 192
// blocks x 8 waves, 1 block/CU (128KB LDS), kslab=768 -> 6-deep pipeline,
// bf16 partials x4 at ws+64.5MB (ends 89.7MB < 256MB); LN2 sums 4 slabs
// (partial sd ~0.2 -> bf16 err ~1e-3 << absmax). Wout stays n64 split-2
// (8-phase would be 96 blocks = 37% fill). attn = R20; QKV/FFN1 = R22.
// ---------------------------------------------------------------------------

typedef __attribute__((ext_vector_type(8)))  short    short8;    // 8 x bf16 (4 VGPR)
typedef __attribute__((ext_vector_type(4)))  float    floatx4;   // 4 x f32 acc
typedef __attribute__((ext_vector_type(16))) float    floatx16;  // 16 x f32 acc (32x32)
typedef __attribute__((ext_vector_type(4)))  unsigned uint4v;

#define QSC 0.18033688f   // 0.125 * log2(e): folded into Q at scatter
#define C2  24.0f         // fixed base-2 softmax offset

__device__ __forceinline__ float b2f(unsigned short u) {
    return __uint_as_float(((unsigned)u) << 16);
}
__device__ __forceinline__ unsigned short f2b(float f) {  // RNE
    unsigned x = __float_as_uint(f);
    return (unsigned short)((x + 0x7fffu + ((x >> 16) & 1u)) >> 16);
}
__device__ __forceinline__ void async_cp16(const void* g, void* l) {
    __builtin_amdgcn_global_load_lds((const __attribute__((address_space(1))) void*)g,
                                     (__attribute__((address_space(3))) void*)l,
                                     16, 0, 0);
}
// pack two f32 -> one dword of 2 x bf16 (RNE); lo = first arg
__device__ __forceinline__ unsigned cvtpk(float lo, float hi) {
    unsigned r;
    asm("v_cvt_pk_bf16_f32 %0, %1, %2" : "=v"(r) : "v"(lo), "v"(hi));
    return r;
}
// swap upper 32 lanes of a with lower 32 lanes of b (both updated)
__device__ __forceinline__ void plswap(unsigned& a, unsigned& b) {
    asm("v_permlane32_swap_b32 %0, %1" : "+v"(a), "+v"(b));
}
// chunk-slot prefix for 512-wide kv chunks: ofs(qb) = sum_{j<qb} ceil((j+1)/4)
__device__ __forceinline__ int chunk_ofs8(int qb) {
    int t = qb >> 2, rem = qb & 3;
    return (t + 1) * (2 * t + rem);
}
// XOR-swizzled [R][64] bf16 tile (16-row x 4-chunk read groups: 2-way max)
__device__ __forceinline__ int swz16(int row, int chunk) {
    return row * 64 + (((chunk ^ (row & 7)) & 7) << 3);
}
// attn swizzle: rows=lane&31 reads, perm varies in row>>3 too
__device__ __forceinline__ int swzB(int row, int chunk) {
    return row * 64 + (((chunk ^ (row & 7) ^ ((row >> 2) & 6)) & 7) << 3);
}

// ---------------- fused prepass: x->bf16 + 4 weight transposes --------------
__global__ __launch_bounds__(256) void prep_all(
    const float* __restrict__ x,    unsigned short* __restrict__ xb,
    const float* __restrict__ Wqkv, unsigned short* __restrict__ wqkvT,
    const float* __restrict__ Wout, unsigned short* __restrict__ woutT,
    const float* __restrict__ W1,   unsigned short* __restrict__ w1T,
    const float* __restrict__ W2,   unsigned short* __restrict__ w2T)
{
    __shared__ float tile[32][33];
    int idx = blockIdx.x;
    int tx = threadIdx.x & 31, ty = threadIdx.x >> 5;
    if (idx >= 6912) {  // cvt x
        int i = (idx - 6912) * 256 + threadIdx.x;
        float4 v = ((const float4*)x)[i];
        ushort4 u;
        u.x = f2b(v.x); u.y = f2b(v.y); u.z = f2b(v.z); u.w = f2b(v.w);
        ((ushort4*)xb)[i] = u;
        return;
    }
    const float* W; unsigned short* Wt; int K, N, bx, by;
    if (idx < 1728)      { W = Wqkv; Wt = wqkvT; K = 768;  N = 2304; bx = idx % 72;        by = idx / 72; }
    else if (idx < 2304) { W = Wout; Wt = woutT; K = 768;  N = 768;  bx = (idx-1728) % 24; by = (idx-1728) / 24; }
    else if (idx < 4608) { W = W1;   Wt = w1T;   K = 768;  N = 3072; bx = (idx-2304) % 96; by = (idx-2304) / 96; }
    else                 { W = W2;   Wt = w2T;   K = 3072; N = 768;  bx = (idx-4608) % 24; by = (idx-4608) / 24; }
    int n0 = bx * 32, k0 = by * 32;
    for (int i = ty; i < 32; i += 8)
        tile[i][tx] = W[(size_t)(k0 + i) * N + n0 + tx];
    __syncthreads();
    for (int i = ty; i < 32; i += 8)
        Wt[(size_t)(n0 + i) * K + k0 + tx] = f2b(tile[tx][i]);
}

// ---------------- 256x256 8-phase MFMA GEMM (QKV / FFN1 / FFN2) -------------
// 512 threads = 8 waves (2M x 4N), per-wave 128x64 out (acc[8][4]), BK=64.
// LDS: 2 buffers x {A half0, A half1, B half0, B half1} x 16KB = 128KB.
// K-range per block: [z*kslab, (z+1)*kslab), kslab%128==0.
// mode 0: bias+relu -> bf16; mode 1: qkv scatter; mode 2: bf16 partial @ z.
__global__ __launch_bounds__(512) void gemm256(
    const unsigned short* __restrict__ A,
    const unsigned short* __restrict__ Bt,
    const float* __restrict__ bias,
    unsigned short* __restrict__ outB,
    int N, int K, int relu, int mode, int kslab)
{
    __shared__ unsigned short L[2][4][8192];   // [buf][A0,A1,B0,B1][128*64]
    const int tid  = threadIdx.x;
    const int gx   = gridDim.x;
    const int nwg  = gx * gridDim.y;           // per-z tiles: %8 == 0
    const int orig = blockIdx.y * gx + blockIdx.x;
    const int qch  = nwg >> 3;
    const int nid  = (orig & 7) * qch + (orig >> 3);   // bijective XCD remap
    const int m0   = (nid / gx) * 256;
    const int n0   = (nid % gx) * 256;
    const int kbeg = blockIdx.z * kslab;
    const int lane = tid & 63;
    const int wave = tid >> 6;                 // 0..7
    const int wr   = wave >> 2;                // A half (0,1)
    const int wc   = wave & 3;                 // 64-col group
    const int fr   = lane & 15;
    const int fq   = lane >> 4;
    const int bpart = 2 + (wc >> 1);           // B half part index
    const int brow0 = (wc & 1) * 64;           // row base within B half

    floatx4 acc[8][4];
    #pragma unroll
    for (int i = 0; i < 8; i++)
        #pragma unroll
        for (int j = 0; j < 4; j++)
            #pragma unroll
            for (int e = 0; e < 4; e++) acc[i][j][e] = 0.f;

// stage one 128x64 half-tile (1024 chunks, 2 per thread), linear LDS dest,
// pre-swizzled global source (inverse of swz16)
#define STGP(BUF, PART, GROW0, BASE, KK)                                       \
    {                                                                          \
        _Pragma("unroll")                                                      \
        for (int q_ = 0; q_ < 2; ++q_) {                                       \
            int c_   = q_ * 512 + tid;                                         \
            int row_ = c_ >> 3;                                                \
            int jj_  = ((c_ & 7) ^ (row_ & 7)) * 8;                            \
            async_cp16(BASE + (size_t)((GROW0) + row_) * K + (KK) + jj_,       \
                       &L[BUF][PART][c_ * 8]);                                 \
        }                                                                      \
    }

// one phase: ds-load subtile -> barrier -> lgkm drain (+sched fence, rule #18)
// -> prio-boosted 16 MFMA -> barrier. bfr reloaded when MP==0.
#define PHASE(KT, MP)                                                          \
    {                                                                          \
        if ((MP) == 0) {                                                       \
            _Pragma("unroll")                                                  \
            for (int nj = 0; nj < 4; ++nj) {                                   \
                bfr[nj][0] = *(const short8*)&L[KT][bpart][swz16(brow0 + nj * 16 + fr, fq)];     \
                bfr[nj][1] = *(const short8*)&L[KT][bpart][swz16(brow0 + nj * 16 + fr, 4 + fq)]; \
            }                                                                  \
        }                                                                      \
        short8 afr[2][2];                                                      \
        _Pragma("unroll")                                                      \
        for (int mm = 0; mm < 2; ++mm) {                                       \
            afr[mm][0] = *(const short8*)&L[KT][wr][swz16(((MP) * 2 + mm) * 16 + fr, fq)];     \
            afr[mm][1] = *(const short8*)&L[KT][wr][swz16(((MP) * 2 + mm) * 16 + fr, 4 + fq)]; \
        }                                                                      \
        __builtin_amdgcn_s_barrier();                                          \
        asm volatile("s_waitcnt lgkmcnt(0)" ::: "memory");                     \
        __builtin_amdgcn_sched_barrier(0);                                     \
        __builtin_amdgcn_s_setprio(1);                                         \
        _Pragma("unroll")                                                      \
        for (int kc = 0; kc < 2; ++kc)                                         \
            _Pragma("unroll")                                                  \
            for (int mm = 0; mm < 2; ++mm)                                     \
                _Pragma("unroll")                                              \
                for (int nj = 0; nj < 4; ++nj)                                 \
                    acc[(MP) * 2 + mm][nj] = __builtin_amdgcn_mfma_f32_16x16x32_bf16( \
                        afr[mm][kc], bfr[nj][kc], acc[(MP) * 2 + mm][nj], 0, 0, 0);   \
        __builtin_amdgcn_s_setprio(0);                                         \
        __builtin_amdgcn_s_barrier();                                          \
    }

    short8 bfr[4][2];
    const int niter = kslab >> 7;              // kslab/128

    // prologue: buf0 <- first K-tile (4 halves), full drain
    STGP(0, 0, m0,       A,  kbeg)
    STGP(0, 1, m0 + 128, A,  kbeg)
    STGP(0, 2, n0,       Bt, kbeg)
    STGP(0, 3, n0 + 128, Bt, kbeg)
    asm volatile("s_waitcnt vmcnt(0)" ::: "memory");
    __builtin_amdgcn_s_barrier();

    for (int it = 0; it < niter; ++it) {
        const int k0   = kbeg + (it << 7);
        const int k1   = k0 + 64;
        const int kn   = k0 + 128;
        const bool more = (it + 1 < niter);    // uniform

        STGP(1, 0, m0,       A,  k1)
        STGP(1, 1, m0 + 128, A,  k1)
        PHASE(0, 0)
        STGP(1, 2, n0,       Bt, k1)
        STGP(1, 3, n0 + 128, Bt, k1)
        PHASE(0, 1)
        PHASE(0, 2)
        asm volatile("s_waitcnt vmcnt(0)" ::: "memory");   // buf1 ready (2-3 phases old)
        PHASE(0, 3)
        if (more) { STGP(0, 0, m0, A, kn) STGP(0, 1, m0 + 128, A, kn) }
        PHASE(1, 0)
        if (more) { STGP(0, 2, n0, Bt, kn) STGP(0, 3, n0 + 128, Bt, kn) }
        PHASE(1, 1)
        PHASE(1, 2)
        if (more) asm volatile("s_waitcnt vmcnt(0)" ::: "memory");  // buf0 ready
        PHASE(1, 3)
    }
#undef STGP
#undef PHASE

    if (mode == 1) {
        // qkv scatter: wave's 64-col block lies in one (which, head) segment
        const int cb    = n0 + wc * 64;
        const int which = (cb >= 1536) ? 2 : (cb >= 768 ? 1 : 0);
        const int hh    = (cb - which * 768) >> 6;
        const float sc  = (which == 0) ? QSC : 1.0f;
        #pragma unroll
        for (int mi = 0; mi < 8; ++mi) {
            #pragma unroll
            for (int nj = 0; nj < 4; ++nj) {
                int d = nj * 16 + fr;
                #pragma unroll
                for (int e = 0; e < 4; ++e) {
                    int row  = m0 + wr * 128 + mi * 16 + fq * 4 + e;
                    int b_   = row >> 11, srow = row & 2047;
                    size_t idx = (size_t)which * 3145728 +
                                 ((size_t)(b_ * 12 + hh) * 2048 + srow) * 64 + d;
                    outB[idx] = f2b(acc[mi][nj][e] * sc);
                }
            }
        }
        return;
    }
    if (mode == 2) {   // bf16 partial at z-slab
        const size_t zoff = (size_t)blockIdx.z * 4096 * N;
        #pragma unroll
        for (int nj = 0; nj < 4; ++nj) {
            int col = n0 + wc * 64 + nj * 16 + fr;
            #pragma unroll
            for (int mi = 0; mi < 8; ++mi) {
                #pragma unroll
                for (int e = 0; e < 4; ++e) {
                    int row = m0 + wr * 128 + mi * 16 + fq * 4 + e;
                    outB[zoff + (size_t)row * N + col] = f2b(acc[mi][nj][e]);
                }
            }
        }
        return;
    }
    #pragma unroll
    for (int nj = 0; nj < 4; ++nj) {
        int col  = n0 + wc * 64 + nj * 16 + fr;
        float bv = bias ? bias[col] : 0.f;
        #pragma unroll
        for (int mi = 0; mi < 8; ++mi) {
            #pragma unroll
            for (int e = 0; e < 4; ++e) {
                int row = m0 + wr * 128 + mi * 16 + fq * 4 + e;
                float v = acc[mi][nj][e] + bv;
                if (relu) v = fmaxf(v, 0.f);
                outB[(size_t)row * N + col] = f2b(v);
            }
        }
    }
}

// ---------------- BN=64 split-K GEMM (Wout) ---------------------------------
// M=4096, N=768 fixed; 128x64 tiles, grid (12,32,2) = 768 blocks = 3/CU exact
// (48KB LDS -> 3 blocks/CU): perfectly balanced, all co-resident, 12 waves/CU.
// Counted-vmcnt dbuf; 6 loads/thread/step. Partials per z-slice: fp32 (outF)
// or bf16 (outB); summed downstream in resid_ln2.
__global__ __launch_bounds__(256) void gemm_n64(
    const unsigned short* __restrict__ A,
    const unsigned short* __restrict__ Bt,
    float* __restrict__ outF,
    unsigned short* __restrict__ outB,
    int K, int kslab)
{
    __shared__ unsigned short As[2][8192];   // [128][64] swizzled
    __shared__ unsigned short Bs[2][4096];   // [64][64]  swizzled
    const int tid  = threadIdx.x;
    const int nwg  = 384;                    // 12 * 32 (per z)
    const int orig = blockIdx.y * 12 + blockIdx.x;
    const int qch  = nwg >> 3;               // 48, rem 0
    const int nid  = (orig & 7) * qch + (orig >> 3);
    const int m0   = (nid / 12) * 128;
    const int n0   = (nid % 12) * 64;
    const int kz   = blockIdx.z;
    const int kbeg = kz * kslab;
    const int kend = kbeg + kslab;
    const int lane = tid & 63;
    const int wave = tid >> 6;
    const int wm   = wave * 32;              // wave's 32 rows; all 64 cols
    const int fr   = lane & 15;
    const int fq   = lane >> 4;

    floatx4 acc[2][4];
    for (int i = 0; i < 2; i++)
        for (int j = 0; j < 4; j++)
            for (int e = 0; e < 4; e++) acc[i][j][e] = 0.f;

#define STAGE64(BUF, KK)                                                       \
    {                                                                          \
        _Pragma("unroll")                                                      \
        for (int r_ = 0; r_ < 4; ++r_) {                                       \
            int c_   = r_ * 256 + tid;                                         \
            int row_ = c_ >> 3;                                                \
            int jj_  = ((c_ & 7) ^ (row_ & 7)) * 8;                            \
            async_cp16(A + (size_t)(m0 + row_) * K + (KK) + jj_, &As[BUF][c_ * 8]); \
        }                                                                      \
        _Pragma("unroll")                                                      \
        for (int r_ = 0; r_ < 2; ++r_) {                                       \
            int c_   = r_ * 256 + tid;       /* 512 chunks = 64 rows x 8 */    \
            int row_ = c_ >> 3;                                                \
            int jj_  = ((c_ & 7) ^ (row_ & 7)) * 8;                            \
            async_cp16(Bt + (size_t)(n0 + row_) * K + (KK) + jj_, &Bs[BUF][c_ * 8]); \
        }                                                                      \
    }

    STAGE64(0, kbeg);
    asm volatile("s_waitcnt vmcnt(0)" ::: "memory");
    __builtin_amdgcn_s_barrier();
    int cur = 0;
    for (int kk = kbeg; kk < kend; kk += 64) {
        const bool more = (kk + 64 < kend);
        if (more) {
            STAGE64(cur ^ 1, kk + 64);          // +6 loads -> next tile
            asm volatile("s_waitcnt vmcnt(6)" ::: "memory");
        } else {
            asm volatile("s_waitcnt vmcnt(0)" ::: "memory");
        }
        __builtin_amdgcn_s_barrier();
        #pragma unroll
        for (int kc = 0; kc < 2; ++kc) {
            short8 a[2], b[4];
            #pragma unroll
            for (int t = 0; t < 2; t++) a[t] = *(const short8*)&As[cur][swz16(wm + t * 16 + fr, kc * 4 + fq)];
            #pragma unroll
            for (int t = 0; t < 4; t++) b[t] = *(const short8*)&Bs[cur][swz16(t * 16 + fr, kc * 4 + fq)];
            #pragma unroll
            for (int i = 0; i < 2; i++)
                #pragma unroll
                for (int j = 0; j < 4; j++)
                    acc[i][j] = __builtin_amdgcn_mfma_f32_16x16x32_bf16(a[i], b[j], acc[i][j], 0, 0, 0);
        }
        asm volatile("s_waitcnt lgkmcnt(0)" ::: "memory");
        __builtin_amdgcn_s_barrier();
        cur ^= 1;
    }
#undef STAGE64

    const size_t zoff = (size_t)kz * 3145728;
    #pragma unroll
    for (int j = 0; j < 4; j++) {
        int col = n0 + j * 16 + fr;
        #pragma unroll
        for (int i = 0; i < 2; i++) {
            int rbase = m0 + wm + i * 16 + fq * 4;
            #pragma unroll
            for (int e = 0; e < 4; e++) {
                size_t idx = zoff + (size_t)(rbase + e) * 768 + col;
                if (outF) outF[idx] = acc[i][j][e];
                else      outB[idx] = f2b(acc[i][j][e]);
            }
        }
    }
}

// ---------------- attention partial (512-wide kv chunks) --------------------
// grid (40, 24) remapped XCD-aware. Swapped QK^T (32x32x16), softmax
// in-register (cvt_pk + permlane32_swap), l-sum = VALU + shfl_xor(32). K via
// global_load_lds (pre-swizzled source); V reg-staged transposed. Epilogue
// restages o via LDS for full-line uint4 stores. Plain launch_bounds(256).
__global__ __launch_bounds__(256) void attn_part(const unsigned short* __restrict__ Qg,
                                                 const unsigned short* __restrict__ Kg,
                                                 const unsigned short* __restrict__ Vg,
                                                 unsigned short* __restrict__ pO,
                                                 float* __restrict__ pL) {
    __shared__ unsigned short Ks[2][4096];   // [64 kv][64 d] swzB
    __shared__ unsigned short Vt[2][4096];   // [64 d][64 kv] swzB (V^T)
    const int tid  = threadIdx.x;
    const int lane = tid & 63;
    const int wave = tid >> 6;
    const int ql   = lane & 31;          // q row within wave block (MFMA col)
    const int hi   = lane >> 5;
    const int wm   = wave * 32;          // wave's 32-row q block
    const int bid  = blockIdx.y * 40 + blockIdx.x;
    const int swz  = (bid & 7) * 120 + (bid >> 3);   // 960 = 8*120, bijective
    const int bh   = swz / 40;
    const int r    = 39 - (swz % 40);    // longest chunks first per XCD
    int qb = 0;
    for (int q_ = 15; q_ >= 0; --q_) if (r >= chunk_ofs8(q_)) { qb = q_; break; }
    const int c     = r - chunk_ofs8(qb);
    const int q0    = qb * 128;
    const int tile0 = 8 * c;
    const int ntk   = min(8, 2 * (qb + 1) - 8 * c);
    const int slot  = bh * 40 + r;
    const unsigned short* Qb = Qg + (size_t)bh * 131072;
    const unsigned short* Kb = Kg + (size_t)bh * 131072;
    const unsigned short* Vb = Vg + (size_t)bh * 131072;
    const int qrow = q0 + wm + ql;       // this lane's global q row

    // Q B-frags: col = q = ql, k = 16*c4 + 8*hi + j
    short8 qf[4];
    {
        const unsigned short* qr = Qb + (size_t)qrow * 64 + hi * 8;
        #pragma unroll
        for (int c4 = 0; c4 < 4; ++c4)
            qf[c4] = *(const short8*)(qr + c4 * 16);
    }

    floatx16 o[2];
    #pragma unroll
    for (int db = 0; db < 2; ++db)
        #pragma unroll
        for (int e = 0; e < 16; ++e) o[db][e] = 0.f;
    float ls[4] = {0.f, 0.f, 0.f, 0.f};

    const int c0 = tid, c1 = tid + 256;
    uint4 vr0, vr1;

// K async stage: dest chunk c linear, source col = (c&7) ^ P(row), P = inverse
// of swzB's perm. Reads via swzB stay unchanged.
#define KSTAGE(BUF, TG)                                                        \
    {                                                                          \
        int base_ = (TG) * 64;                                                 \
        int r0_ = c0 >> 3, j0_ = (c0 & 7) ^ (r0_ & 7) ^ ((r0_ >> 2) & 6);      \
        int r1_ = c1 >> 3, j1_ = (c1 & 7) ^ (r1_ & 7) ^ ((r1_ >> 2) & 6);      \
        async_cp16(Kb + (size_t)(base_ + r0_) * 64 + (j0_ & 7) * 8,            \
                   &Ks[BUF][c0 * 8]);                                          \
        async_cp16(Kb + (size_t)(base_ + r1_) * 64 + (j1_ & 7) * 8,            \
                   &Ks[BUF][c1 * 8]);                                          \
    }
#define LOADV(TG)                                                              \
    {                                                                          \
        int base = (TG) * 64;                                                  \
        vr0 = *(const uint4*)(Vb + (size_t)(base + (c0 & 63)) * 64 + (c0 >> 6) * 8); \
        vr1 = *(const uint4*)(Vb + (size_t)(base + (c1 & 63)) * 64 + (c1 >> 6) * 8); \
    }
// Vt transposed write: logical (row=(c>>6)*8+i, kv=c&63), swzB element address
#define WRITEV(BUF)                                                            \
    {                                                                          \
        unsigned short t0[8]; *(uint4*)t0 = vr0;                               \
        _Pragma("unroll") for (int i_ = 0; i_ < 8; ++i_) {                     \
            int rv = (c0 >> 6) * 8 + i_;                                       \
            Vt[BUF][rv * 64 + (((((c0 >> 3) & 7) ^ i_ ^ ((rv >> 2) & 6)) & 7) << 3) + (c0 & 7)] = t0[i_]; \
        }                                                                      \
        unsigned short t1[8]; *(uint4*)t1 = vr1;                               \
        _Pragma("unroll") for (int i_ = 0; i_ < 8; ++i_) {                     \
            int rv = (c1 >> 6) * 8 + i_;                                       \
            Vt[BUF][rv * 64 + (((((c1 >> 3) & 7) ^ i_ ^ ((rv >> 2) & 6)) & 7) << 3) + (c1 & 7)] = t1[i_]; \
        }                                                                      \
    }

    KSTAGE(0, tile0);
    LOADV(tile0);
    WRITEV(0);
    __syncthreads();                 // drains K DMA (vmcnt0) + V writes

    for (int kt = 0; kt < ntk; ++kt) {
        const int  tg   = tile0 + kt;
        const int  cur  = kt & 1;
        const bool more = (kt + 1 < ntk);
        if (more) {
            KSTAGE(cur ^ 1, tg + 1);   // DMA into buffer freed by prev barrier
            LOADV(tg + 1);
        }

        #pragma unroll
        for (int bb = 0; bb < 2; ++bb) {
            // ---- QK^T (swapped): s^T[kv][q], A = K rows, B = Q cols ----
            short8 kf[4];
            #pragma unroll
            for (int c4 = 0; c4 < 4; ++c4)
                kf[c4] = *(const short8*)&Ks[cur][swzB(32 * bb + ql, 2 * c4 + hi)];
            floatx16 s;
            #pragma unroll
            for (int e = 0; e < 16; ++e) s[e] = 0.f;
            #pragma unroll
            for (int c4 = 0; c4 < 4; ++c4)
                s = __builtin_amdgcn_mfma_f32_32x32x16_bf16(kf[c4], qf[c4], s, 0, 0, 0);

            // ---- softmax: p = 2^(s - C2); causal mask -> 0 ----
            const int  kvb = tg * 64 + 32 * bb + 4 * hi;
            const bool nm  = (tg * 64 + 32 * bb + 31) > (q0 + wm);
            if (nm) {
                #pragma unroll
                for (int e = 0; e < 16; ++e)
                    if (kvb + (e & 3) + 8 * (e >> 2) > qrow) s[e] = -1e30f;
            }
            float pv[16];
            #pragma unroll
            for (int e = 0; e < 16; ++e) {
                pv[e] = __builtin_amdgcn_exp2f(s[e] - C2);
                ls[e & 3] += pv[e];
            }

            // ---- P -> bf16 A-frags in-register ----
            unsigned w[8];
            #pragma unroll
            for (int m = 0; m < 4; ++m) {
                w[2 * m]     = cvtpk(pv[4 * m],     pv[4 * m + 1]);
                w[2 * m + 1] = cvtpk(pv[4 * m + 2], pv[4 * m + 3]);
            }
            plswap(w[0], w[2]);   // frag g=0: words 0,2
            plswap(w[1], w[3]);   // frag g=0: words 1,3
            plswap(w[4], w[6]);   // frag g=1: words 0,2
            plswap(w[5], w[7]);   // frag g=1: words 1,3
            uint4v u0 = {w[0], w[1], w[2], w[3]};
            uint4v u1 = {w[4], w[5], w[6], w[7]};
            short8 pa0 = __builtin_bit_cast(short8, u0);
            short8 pa1 = __builtin_bit_cast(short8, u1);

            // ---- PV: A = P frags, B = V^T (col = d, k = kv) ----
            #pragma unroll
            for (int db = 0; db < 2; ++db) {
                short8 vf0 = *(const short8*)&Vt[cur][swzB(32 * db + ql, 4 * bb + hi)];
                short8 vf1 = *(const short8*)&Vt[cur][swzB(32 * db + ql, 4 * bb + 2 + hi)];
                o[db] = __builtin_amdgcn_mfma_f32_32x32x16_bf16(pa0, vf0, o[db], 0, 0, 0);
                o[db] = __builtin_amdgcn_mfma_f32_32x32x16_bf16(pa1, vf1, o[db], 0, 0, 0);
            }
        }

        if (more) {
            WRITEV(cur ^ 1);
            __syncthreads();          // drains K DMA + V writes; frees cur
        }
    }
#undef KSTAGE
#undef LOADV
#undef WRITEV

    float lsum = (ls[0] + ls[1]) + (ls[2] + ls[3]);
    lsum += __shfl_xor(lsum, 32);
    if (lane < 32)
        pL[(size_t)slot * 128 + wm + ql] = lsum;

    // ---- epilogue: restage o (bf16) in dead Ks LDS, then full-line stores ----
    __syncthreads();                       // all waves done reading Ks/Vt
    unsigned short* Ost = &Ks[0][0];       // 16KB: [128][64], chunk ^ (row&7)
    #pragma unroll
    for (int db = 0; db < 2; ++db)
        #pragma unroll
        for (int e = 0; e < 16; ++e) {
            int row = wm + (e & 3) + 8 * (e >> 2) + 4 * hi;
            int col = db * 32 + ql;
            Ost[row * 64 + ((((col >> 3) ^ (row & 7)) & 7) << 3) + (col & 7)] =
                f2b(o[db][e]);
        }
    __syncthreads();
    #pragma unroll
    for (int p = 0; p < 4; ++p) {
        int chunk = p * 256 + tid;         // 1024 chunks = 128 rows x 8
        int row = chunk >> 3, cc = chunk & 7;
        uint4 val = *(const uint4*)&Ost[row * 64 + (((cc ^ (row & 7)) & 7) << 3)];
        *(uint4*)(pO + ((size_t)slot * 128 + row) * 64 + cc * 8) = val;
    }
}

// ---------------- attention combine (fixed base: plain sums) ----------------
// grid (16, 24); merges <=4 chunks of 512 kv each.
__global__ __launch_bounds__(256) void attn_combine(const unsigned short* __restrict__ pO,
                                                    const float* __restrict__ pL,
                                                    unsigned short* __restrict__ ctx) {
    const int qb  = blockIdx.x;
    const int bh  = blockIdx.y;
    const int b   = bh / 12, h = bh % 12;
    const int nch = (qb >> 2) + 1;             // ceil((qb+1)/4)
    const int slot0 = bh * 40 + chunk_ofs8(qb);
    const int tid = threadIdx.x;
    const int row = tid >> 1;
    const int col0 = (tid & 1) * 32;

    float L = 0.f;
    for (int i = 0; i < nch; ++i)
        L += pL[(size_t)(slot0 + i) * 128 + row];

    float acc[32];
    #pragma unroll
    for (int j = 0; j < 32; ++j) acc[j] = 0.f;
    for (int i = 0; i < nch; ++i) {
        const unsigned short* p = pO + ((size_t)(slot0 + i) * 128 + row) * 64 + col0;
        #pragma unroll
        for (int v4 = 0; v4 < 4; ++v4) {
            uint4 u = *(const uint4*)(p + v4 * 8);
            unsigned short t[8]; *(uint4*)t = u;
            #pragma unroll
            for (int j = 0; j < 8; ++j) acc[v4 * 8 + j] += b2f(t[j]);
        }
    }
    float inv = 1.f / L;
    unsigned short* orow = ctx + ((size_t)(b * 2048 + qb * 128 + row)) * 768 + h * 64 + col0;
    #pragma unroll
    for (int v4 = 0; v4 < 4; ++v4) {
        unsigned short t[8];
        #pragma unroll
        for (int j = 0; j < 8; ++j) t[j] = f2b(acc[v4 * 8 + j] * inv);
        *(uint4*)(orow + v4 * 8) = *(uint4*)t;
    }
}

// ---------------- fused reduce + bias + residual + LayerNorm ----------------
// Partials: fp32 via Pf or bf16 via Pb (exactly one non-null when nsplit>0).
__global__ __launch_bounds__(256) void resid_ln2(const float* __restrict__ X,
                                                 const float* __restrict__ Pf,
                                                 const unsigned short* __restrict__ Pb,
                                                 int nsplit,
                                                 const float* __restrict__ bv,
                                                 const float* __restrict__ gain,
                                                 const float* __restrict__ beta,
                                                 float* __restrict__ outF,
                                                 unsigned short* __restrict__ outB) {
    const int row = blockIdx.x;
    const int t   = threadIdx.x;
    const size_t off = (size_t)row * 768;
    float v[3];
    #pragma unroll
    for (int i = 0; i < 3; i++) {
        size_t c = off + t + i * 256;
        float r = X[c] + bv[t + i * 256];
        if (Pf) {
            for (int p = 0; p < nsplit; ++p) r += Pf[(size_t)p * 3145728 + c];
        } else {
            for (int p = 0; p < nsplit; ++p) r += b2f(Pb[(size_t)p * 3145728 + c]);
        }
        v[i] = r;
    }
    float s  = v[0] + v[1] + v[2];
    float s2 = v[0] * v[0] + v[1] * v[1] + v[2] * v[2];
    #pragma unroll
    for (int o2 = 32; o2 > 0; o2 >>= 1) {
        s  += __shfl_down(s,  o2);
        s2 += __shfl_down(s2, o2);
    }
    __shared__ float rs[4], rq[4];
    if ((t & 63) == 0) { rs[t >> 6] = s; rq[t >> 6] = s2; }
    __syncthreads();
    float S    = rs[0] + rs[1] + rs[2] + rs[3];
    float S2   = rq[0] + rq[1] + rq[2] + rq[3];
    float mean = S * (1.0f / 768.0f);
    float var  = S2 * (1.0f / 768.0f) - mean * mean;
    float inv  = rsqrtf(var + 1e-5f);
    #pragma unroll
    for (int i = 0; i < 3; i++) {
        int c   = t + i * 256;
        float y = gain[c] * (v[i] - mean) * inv + beta[c];
        if (outF) outF[off + c] = y;
        if (outB) outB[off + c] = f2b(y);
    }
}

// ---------------------------------------------------------------------------
extern "C" void kernel_launch(void* const* d_in, const int* in_sizes, int n_in,
                              void* d_out, int out_size, void* d_ws, size_t ws_size,
                              hipStream_t stream) {
    const float* x    = (const float*)d_in[0];
    const float* Wqkv = (const float*)d_in[1];
    const float* Wout = (const float*)d_in[2];
    const float* bout = (const float*)d_in[3];
    const float* W1   = (const float*)d_in[4];
    const float* b1   = (const float*)d_in[5];
    const float* W2   = (const float*)d_in[6];
    const float* b2   = (const float*)d_in[7];
    const float* g1   = (const float*)d_in[8];
    const float* be1  = (const float*)d_in[9];
    const float* g2   = (const float*)d_in[10];
    const float* be2  = (const float*)d_in[11];
    float* out = (float*)d_out;

    // workspace layout (bytes), liveness-aliased; alloc is 256MB (R23 fill
    // evidence) -> W2Pb 4-slab region beyond old 83MB peak is safe.
    char* ws = (char*)d_ws;
    unsigned short* wqkvT  = (unsigned short*)(ws + 0);         // 3.5M  ->QKV
    unsigned short* woutT  = (unsigned short*)(ws + 3538944);   // 1.2M  ->Wout
    unsigned short* w1T    = (unsigned short*)(ws + 4718592);   // 4.7M  ->W1
    unsigned short* w2T    = (unsigned short*)(ws + 9437184);   // 4.7M  ->W2
    unsigned short* xb     = (unsigned short*)(ws + 14155776);  // 6.3M  ->QKV
    unsigned short* qkvG   = (unsigned short*)(ws + 20447232);  // 18.9M ->attn_part
    unsigned short* Qg     = qkvG;
    unsigned short* Kg     = qkvG + 3145728;
    unsigned short* Vg     = qkvG + 6291456;
    unsigned short* pO     = (unsigned short*)(ws + 39321600);  // 15.7M ->combine (960 slots)
    float*          pL     = (float*)(ws + 67633152);           // 0.49M ->combine
    unsigned short* ctxb   = (unsigned short*)(ws + 14155776);  // 6.3M  combine->Wout (xb dead)
    float*          WoutP  = (float*)(ws + 39321600);           // 2x12.6M Wout->LN1 (pO dead)
    float*          h      = (float*)(ws + 20447232);           // 12.6M LN1->LN2 (qkvG dead)
    unsigned short* hb     = (unsigned short*)(ws + 77070336);  // 6.3M  LN1->W1
    unsigned short* ffb    = (unsigned short*)(ws + 39321600);  // 25.2M W1->W2 (WoutP dead)
    unsigned short* W2Pb   = (unsigned short*)(ws + 90177536);  // 4x6.3M bf16 W2->LN2; ends 115.3M

    // 1) fused prepass
    prep_all<<<9984, 256, 0, stream>>>(x, xb, Wqkv, wqkvT, Wout, woutT, W1, w1T, W2, w2T);
    // 2) QKV projection (256^2 8-phase) -> Q/K/V [bh][s][64] bf16 (Q pre-scaled)
    gemm256<<<dim3(9, 16), 512, 0, stream>>>(xb, wqkvT, nullptr, qkvG, 2304, 768, 0, 1, 768);
    // 3) kv-split flash attention (512-wide chunks) + combine -> ctx bf16
    attn_part<<<dim3(40, 24), 256, 0, stream>>>(Qg, Kg, Vg, pO, pL);
    attn_combine<<<dim3(16, 24), 256, 0, stream>>>(pO, pL, ctxb);
    // 4) out projection, split-K=2 -> fp32 partials (768 blocks = 3/CU exact)
    gemm_n64<<<dim3(12, 32, 2), 256, 0, stream>>>(ctxb, woutT, WoutP, nullptr, 768, 384);
    // 5) h = LN(x + sum WoutP + bout) -> fp32 + bf16
    resid_ln2<<<4096, 256, 0, stream>>>(x, WoutP, nullptr, 2, bout, g1, be1, h, hb);
    // 6) ff = relu(h @ W1 + b1) (256^2 8-phase) -> bf16
    gemm256<<<dim3(12, 16), 512, 0, stream>>>(hb, w1T, b1, ffb, 3072, 768, 1, 0, 768);
    // 7) ff2 = ff @ W2 (256^2 8-phase, split-K=4) -> bf16 partials
    gemm256<<<dim3(3, 16, 4), 512, 0, stream>>>(ffb, w2T, nullptr, W2Pb, 768, 3072, 0, 2, 768);
    // 8) out = LN(h + sum W2Pb + b2) -> fp32
    resid_ln2<<<4096, 256, 0, stream>>>(h, nullptr, W2Pb, 4, b2, g2, be2, out, nullptr);
}

// Round 12
// 267.754 us; speedup vs baseline: 1.0337x; 1.0337x over previous
//
#include <hip/hip_runtime.h>

// ---------------------------------------------------------------------------
// TransformerBlock: B=2,S=2048,D=768,H=12,DH=64,DFF=3072, causal attn, 2x LN
// Round 25: revert FFN2 to R23 gemm_n64 split-K=2. R24's FFN2-8phase lost
// ~7.5us: grid (3,16,4)=192 blocks = 1 block/CU (128KB LDS) -> 75% fill and
// NO co-resident queue to hide the phase-3/7 vmcnt gates (8-phase needs >=2
// blocks/CU of queue; narrow-N shapes at 256^2 tiles can't provide it), plus
// LN2 partial reads doubled. attn micro: QK accumulator initialized to -C2
// (MFMA C-in is additive) -> kills 32 v_sub per tile per lane in softmax
// (VALUBusy 37% is the busiest pipe there).
// QKV/FFN1 = R22 8-phase gemm256; Wout = n64 split-2; attn = R20 otherwise.
// ---------------------------------------------------------------------------

typedef __attribute__((ext_vector_type(8)))  short    short8;    // 8 x bf16 (4 VGPR)
typedef __attribute__((ext_vector_type(4)))  float    floatx4;   // 4 x f32 acc
typedef __attribute__((ext_vector_type(16))) float    floatx16;  // 16 x f32 acc (32x32)
typedef __attribute__((ext_vector_type(4)))  unsigned uint4v;

#define QSC 0.18033688f   // 0.125 * log2(e): folded into Q at scatter
#define C2  24.0f         // fixed base-2 softmax offset

__device__ __forceinline__ float b2f(unsigned short u) {
    return __uint_as_float(((unsigned)u) << 16);
}
__device__ __forceinline__ unsigned short f2b(float f) {  // RNE
    unsigned x = __float_as_uint(f);
    return (unsigned short)((x + 0x7fffu + ((x >> 16) & 1u)) >> 16);
}
__device__ __forceinline__ void async_cp16(const void* g, void* l) {
    __builtin_amdgcn_global_load_lds((const __attribute__((address_space(1))) void*)g,
                                     (__attribute__((address_space(3))) void*)l,
                                     16, 0, 0);
}
// pack two f32 -> one dword of 2 x bf16 (RNE); lo = first arg
__device__ __forceinline__ unsigned cvtpk(float lo, float hi) {
    unsigned r;
    asm("v_cvt_pk_bf16_f32 %0, %1, %2" : "=v"(r) : "v"(lo), "v"(hi));
    return r;
}
// swap upper 32 lanes of a with lower 32 lanes of b (both updated)
__device__ __forceinline__ void plswap(unsigned& a, unsigned& b) {
    asm("v_permlane32_swap_b32 %0, %1" : "+v"(a), "+v"(b));
}
// chunk-slot prefix for 512-wide kv chunks: ofs(qb) = sum_{j<qb} ceil((j+1)/4)
__device__ __forceinline__ int chunk_ofs8(int qb) {
    int t = qb >> 2, rem = qb & 3;
    return (t + 1) * (2 * t + rem);
}
// XOR-swizzled [R][64] bf16 tile (16-row x 4-chunk read groups: 2-way max)
__device__ __forceinline__ int swz16(int row, int chunk) {
    return row * 64 + (((chunk ^ (row & 7)) & 7) << 3);
}
// attn swizzle: rows=lane&31 reads, perm varies in row>>3 too
__device__ __forceinline__ int swzB(int row, int chunk) {
    return row * 64 + (((chunk ^ (row & 7) ^ ((row >> 2) & 6)) & 7) << 3);
}

// ---------------- fused prepass: x->bf16 + 4 weight transposes --------------
__global__ __launch_bounds__(256) void prep_all(
    const float* __restrict__ x,    unsigned short* __restrict__ xb,
    const float* __restrict__ Wqkv, unsigned short* __restrict__ wqkvT,
    const float* __restrict__ Wout, unsigned short* __restrict__ woutT,
    const float* __restrict__ W1,   unsigned short* __restrict__ w1T,
    const float* __restrict__ W2,   unsigned short* __restrict__ w2T)
{
    __shared__ float tile[32][33];
    int idx = blockIdx.x;
    int tx = threadIdx.x & 31, ty = threadIdx.x >> 5;
    if (idx >= 6912) {  // cvt x
        int i = (idx - 6912) * 256 + threadIdx.x;
        float4 v = ((const float4*)x)[i];
        ushort4 u;
        u.x = f2b(v.x); u.y = f2b(v.y); u.z = f2b(v.z); u.w = f2b(v.w);
        ((ushort4*)xb)[i] = u;
        return;
    }
    const float* W; unsigned short* Wt; int K, N, bx, by;
    if (idx < 1728)      { W = Wqkv; Wt = wqkvT; K = 768;  N = 2304; bx = idx % 72;        by = idx / 72; }
    else if (idx < 2304) { W = Wout; Wt = woutT; K = 768;  N = 768;  bx = (idx-1728) % 24; by = (idx-1728) / 24; }
    else if (idx < 4608) { W = W1;   Wt = w1T;   K = 768;  N = 3072; bx = (idx-2304) % 96; by = (idx-2304) / 96; }
    else                 { W = W2;   Wt = w2T;   K = 3072; N = 768;  bx = (idx-4608) % 24; by = (idx-4608) / 24; }
    int n0 = bx * 32, k0 = by * 32;
    for (int i = ty; i < 32; i += 8)
        tile[i][tx] = W[(size_t)(k0 + i) * N + n0 + tx];
    __syncthreads();
    for (int i = ty; i < 32; i += 8)
        Wt[(size_t)(n0 + i) * K + k0 + tx] = f2b(tile[tx][i]);
}

// ---------------- 256x256 8-phase MFMA GEMM (QKV / FFN1) --------------------
// 512 threads = 8 waves (2M x 4N), per-wave 128x64 out (acc[8][4]), BK=64.
// LDS: 2 buffers x {A half0, A half1, B half0, B half1} x 16KB = 128KB.
// mode 0: bias+relu -> bf16; mode 1: qkv scatter.
__global__ __launch_bounds__(512) void gemm256(
    const unsigned short* __restrict__ A,
    const unsigned short* __restrict__ Bt,
    const float* __restrict__ bias,
    unsigned short* __restrict__ outB,
    int N, int K, int relu, int mode)
{
    __shared__ unsigned short L[2][4][8192];   // [buf][A0,A1,B0,B1][128*64]
    const int tid  = threadIdx.x;
    const int gx   = gridDim.x;
    const int nwg  = gx * gridDim.y;           // 144 or 192: %8 == 0
    const int orig = blockIdx.y * gx + blockIdx.x;
    const int qch  = nwg >> 3;
    const int nid  = (orig & 7) * qch + (orig >> 3);   // bijective XCD remap
    const int m0   = (nid / gx) * 256;
    const int n0   = (nid % gx) * 256;
    const int lane = tid & 63;
    const int wave = tid >> 6;                 // 0..7
    const int wr   = wave >> 2;                // A half (0,1)
    const int wc   = wave & 3;                 // 64-col group
    const int fr   = lane & 15;
    const int fq   = lane >> 4;
    const int bpart = 2 + (wc >> 1);           // B half part index
    const int brow0 = (wc & 1) * 64;           // row base within B half

    floatx4 acc[8][4];
    #pragma unroll
    for (int i = 0; i < 8; i++)
        #pragma unroll
        for (int j = 0; j < 4; j++)
            #pragma unroll
            for (int e = 0; e < 4; e++) acc[i][j][e] = 0.f;

// stage one 128x64 half-tile (1024 chunks, 2 per thread), linear LDS dest,
// pre-swizzled global source (inverse of swz16)
#define STGP(BUF, PART, GROW0, BASE, KK)                                       \
    {                                                                          \
        _Pragma("unroll")                                                      \
        for (int q_ = 0; q_ < 2; ++q_) {                                       \
            int c_   = q_ * 512 + tid;                                         \
            int row_ = c_ >> 3;                                                \
            int jj_  = ((c_ & 7) ^ (row_ & 7)) * 8;                            \
            async_cp16(BASE + (size_t)((GROW0) + row_) * K + (KK) + jj_,       \
                       &L[BUF][PART][c_ * 8]);                                 \
        }                                                                      \
    }

// one phase: ds-load subtile -> barrier -> lgkm drain (+sched fence, rule #18)
// -> prio-boosted 16 MFMA -> barrier. bfr reloaded when MP==0.
#define PHASE(KT, MP)                                                          \
    {                                                                          \
        if ((MP) == 0) {                                                       \
            _Pragma("unroll")                                                  \
            for (int nj = 0; nj < 4; ++nj) {                                   \
                bfr[nj][0] = *(const short8*)&L[KT][bpart][swz16(brow0 + nj * 16 + fr, fq)];     \
                bfr[nj][1] = *(const short8*)&L[KT][bpart][swz16(brow0 + nj * 16 + fr, 4 + fq)]; \
            }                                                                  \
        }                                                                      \
        short8 afr[2][2];                                                      \
        _Pragma("unroll")                                                      \
        for (int mm = 0; mm < 2; ++mm) {                                       \
            afr[mm][0] = *(const short8*)&L[KT][wr][swz16(((MP) * 2 + mm) * 16 + fr, fq)];     \
            afr[mm][1] = *(const short8*)&L[KT][wr][swz16(((MP) * 2 + mm) * 16 + fr, 4 + fq)]; \
        }                                                                      \
        __builtin_amdgcn_s_barrier();                                          \
        asm volatile("s_waitcnt lgkmcnt(0)" ::: "memory");                     \
        __builtin_amdgcn_sched_barrier(0);                                     \
        __builtin_amdgcn_s_setprio(1);                                         \
        _Pragma("unroll")                                                      \
        for (int kc = 0; kc < 2; ++kc)                                         \
            _Pragma("unroll")                                                  \
            for (int mm = 0; mm < 2; ++mm)                                     \
                _Pragma("unroll")                                              \
                for (int nj = 0; nj < 4; ++nj)                                 \
                    acc[(MP) * 2 + mm][nj] = __builtin_amdgcn_mfma_f32_16x16x32_bf16( \
                        afr[mm][kc], bfr[nj][kc], acc[(MP) * 2 + mm][nj], 0, 0, 0);   \
        __builtin_amdgcn_s_setprio(0);                                         \
        __builtin_amdgcn_s_barrier();                                          \
    }

    short8 bfr[4][2];
    const int niter = K >> 7;                  // K/128 (768 -> 6)

    // prologue: buf0 <- K-tile 0 (4 halves), full drain
    STGP(0, 0, m0,       A,  0)
    STGP(0, 1, m0 + 128, A,  0)
    STGP(0, 2, n0,       Bt, 0)
    STGP(0, 3, n0 + 128, Bt, 0)
    asm volatile("s_waitcnt vmcnt(0)" ::: "memory");
    __builtin_amdgcn_s_barrier();

    for (int it = 0; it < niter; ++it) {
        const int k0   = it << 7;
        const int k1   = k0 + 64;
        const int kn   = k0 + 128;
        const bool more = (it + 1 < niter);    // uniform

        STGP(1, 0, m0,       A,  k1)
        STGP(1, 1, m0 + 128, A,  k1)
        PHASE(0, 0)
        STGP(1, 2, n0,       Bt, k1)
        STGP(1, 3, n0 + 128, Bt, k1)
        PHASE(0, 1)
        PHASE(0, 2)
        asm volatile("s_waitcnt vmcnt(0)" ::: "memory");   // buf1 ready (2-3 phases old)
        PHASE(0, 3)
        if (more) { STGP(0, 0, m0, A, kn) STGP(0, 1, m0 + 128, A, kn) }
        PHASE(1, 0)
        if (more) { STGP(0, 2, n0, Bt, kn) STGP(0, 3, n0 + 128, Bt, kn) }
        PHASE(1, 1)
        PHASE(1, 2)
        if (more) asm volatile("s_waitcnt vmcnt(0)" ::: "memory");  // buf0 ready
        PHASE(1, 3)
    }
#undef STGP
#undef PHASE

    if (mode == 1) {
        // qkv scatter: wave's 64-col block lies in one (which, head) segment
        const int cb    = n0 + wc * 64;
        const int which = (cb >= 1536) ? 2 : (cb >= 768 ? 1 : 0);
        const int hh    = (cb - which * 768) >> 6;
        const float sc  = (which == 0) ? QSC : 1.0f;
        #pragma unroll
        for (int mi = 0; mi < 8; ++mi) {
            #pragma unroll
            for (int nj = 0; nj < 4; ++nj) {
                int d = nj * 16 + fr;
                #pragma unroll
                for (int e = 0; e < 4; ++e) {
                    int row  = m0 + wr * 128 + mi * 16 + fq * 4 + e;
                    int b_   = row >> 11, srow = row & 2047;
                    size_t idx = (size_t)which * 3145728 +
                                 ((size_t)(b_ * 12 + hh) * 2048 + srow) * 64 + d;
                    outB[idx] = f2b(acc[mi][nj][e] * sc);
                }
            }
        }
        return;
    }
    #pragma unroll
    for (int nj = 0; nj < 4; ++nj) {
        int col  = n0 + wc * 64 + nj * 16 + fr;
        float bv = bias ? bias[col] : 0.f;
        #pragma unroll
        for (int mi = 0; mi < 8; ++mi) {
            #pragma unroll
            for (int e = 0; e < 4; ++e) {
                int row = m0 + wr * 128 + mi * 16 + fq * 4 + e;
                float v = acc[mi][nj][e] + bv;
                if (relu) v = fmaxf(v, 0.f);
                outB[(size_t)row * N + col] = f2b(v);
            }
        }
    }
}

// ---------------- BN=64 split-K GEMM (Wout / FFN2) --------------------------
// M=4096, N=768 fixed; 128x64 tiles, grid (12,32,2) = 768 blocks = 3/CU exact
// (48KB LDS -> 3 blocks/CU): perfectly balanced, all co-resident, 12 waves/CU.
// Counted-vmcnt dbuf; 6 loads/thread/step. Partials per z-slice: fp32 (outF)
// or bf16 (outB); summed downstream in resid_ln2.
__global__ __launch_bounds__(256) void gemm_n64(
    const unsigned short* __restrict__ A,
    const unsigned short* __restrict__ Bt,
    float* __restrict__ outF,
    unsigned short* __restrict__ outB,
    int K, int kslab)
{
    __shared__ unsigned short As[2][8192];   // [128][64] swizzled
    __shared__ unsigned short Bs[2][4096];   // [64][64]  swizzled
    const int tid  = threadIdx.x;
    const int nwg  = 384;                    // 12 * 32 (per z)
    const int orig = blockIdx.y * 12 + blockIdx.x;
    const int qch  = nwg >> 3;               // 48, rem 0
    const int nid  = (orig & 7) * qch + (orig >> 3);
    const int m0   = (nid / 12) * 128;
    const int n0   = (nid % 12) * 64;
    const int kz   = blockIdx.z;
    const int kbeg = kz * kslab;
    const int kend = kbeg + kslab;
    const int lane = tid & 63;
    const int wave = tid >> 6;
    const int wm   = wave * 32;              // wave's 32 rows; all 64 cols
    const int fr   = lane & 15;
    const int fq   = lane >> 4;

    floatx4 acc[2][4];
    for (int i = 0; i < 2; i++)
        for (int j = 0; j < 4; j++)
            for (int e = 0; e < 4; e++) acc[i][j][e] = 0.f;

#define STAGE64(BUF, KK)                                                       \
    {                                                                          \
        _Pragma("unroll")                                                      \
        for (int r_ = 0; r_ < 4; ++r_) {                                       \
            int c_   = r_ * 256 + tid;                                         \
            int row_ = c_ >> 3;                                                \
            int jj_  = ((c_ & 7) ^ (row_ & 7)) * 8;                            \
            async_cp16(A + (size_t)(m0 + row_) * K + (KK) + jj_, &As[BUF][c_ * 8]); \
        }                                                                      \
        _Pragma("unroll")                                                      \
        for (int r_ = 0; r_ < 2; ++r_) {                                       \
            int c_   = r_ * 256 + tid;       /* 512 chunks = 64 rows x 8 */    \
            int row_ = c_ >> 3;                                                \
            int jj_  = ((c_ & 7) ^ (row_ & 7)) * 8;                            \
            async_cp16(Bt + (size_t)(n0 + row_) * K + (KK) + jj_, &Bs[BUF][c_ * 8]); \
        }                                                                      \
    }

    STAGE64(0, kbeg);
    asm volatile("s_waitcnt vmcnt(0)" ::: "memory");
    __builtin_amdgcn_s_barrier();
    int cur = 0;
    for (int kk = kbeg; kk < kend; kk += 64) {
        const bool more = (kk + 64 < kend);
        if (more) {
            STAGE64(cur ^ 1, kk + 64);          // +6 loads -> next tile
            asm volatile("s_waitcnt vmcnt(6)" ::: "memory");
        } else {
            asm volatile("s_waitcnt vmcnt(0)" ::: "memory");
        }
        __builtin_amdgcn_s_barrier();
        #pragma unroll
        for (int kc = 0; kc < 2; ++kc) {
            short8 a[2], b[4];
            #pragma unroll
            for (int t = 0; t < 2; t++) a[t] = *(const short8*)&As[cur][swz16(wm + t * 16 + fr, kc * 4 + fq)];
            #pragma unroll
            for (int t = 0; t < 4; t++) b[t] = *(const short8*)&Bs[cur][swz16(t * 16 + fr, kc * 4 + fq)];
            #pragma unroll
            for (int i = 0; i < 2; i++)
                #pragma unroll
                for (int j = 0; j < 4; j++)
                    acc[i][j] = __builtin_amdgcn_mfma_f32_16x16x32_bf16(a[i], b[j], acc[i][j], 0, 0, 0);
        }
        asm volatile("s_waitcnt lgkmcnt(0)" ::: "memory");
        __builtin_amdgcn_s_barrier();
        cur ^= 1;
    }
#undef STAGE64

    const size_t zoff = (size_t)kz * 3145728;
    #pragma unroll
    for (int j = 0; j < 4; j++) {
        int col = n0 + j * 16 + fr;
        #pragma unroll
        for (int i = 0; i < 2; i++) {
            int rbase = m0 + wm + i * 16 + fq * 4;
            #pragma unroll
            for (int e = 0; e < 4; e++) {
                size_t idx = zoff + (size_t)(rbase + e) * 768 + col;
                if (outF) outF[idx] = acc[i][j][e];
                else      outB[idx] = f2b(acc[i][j][e]);
            }
        }
    }
}

// ---------------- attention partial (512-wide kv chunks) --------------------
// grid (40, 24) remapped XCD-aware. Swapped QK^T (32x32x16), softmax
// in-register (cvt_pk + permlane32_swap), l-sum = VALU + shfl_xor(32). K via
// global_load_lds (pre-swizzled source); V reg-staged transposed. QK acc
// initialized to -C2 (saves 32 v_sub/tile/lane). Epilogue restages o via LDS
// for full-line uint4 stores. Plain launch_bounds(256).
__global__ __launch_bounds__(256) void attn_part(const unsigned short* __restrict__ Qg,
                                                 const unsigned short* __restrict__ Kg,
                                                 const unsigned short* __restrict__ Vg,
                                                 unsigned short* __restrict__ pO,
                                                 float* __restrict__ pL) {
    __shared__ unsigned short Ks[2][4096];   // [64 kv][64 d] swzB
    __shared__ unsigned short Vt[2][4096];   // [64 d][64 kv] swzB (V^T)
    const int tid  = threadIdx.x;
    const int lane = tid & 63;
    const int wave = tid >> 6;
    const int ql   = lane & 31;          // q row within wave block (MFMA col)
    const int hi   = lane >> 5;
    const int wm   = wave * 32;          // wave's 32-row q block
    const int bid  = blockIdx.y * 40 + blockIdx.x;
    const int swz  = (bid & 7) * 120 + (bid >> 3);   // 960 = 8*120, bijective
    const int bh   = swz / 40;
    const int r    = 39 - (swz % 40);    // longest chunks first per XCD
    int qb = 0;
    for (int q_ = 15; q_ >= 0; --q_) if (r >= chunk_ofs8(q_)) { qb = q_; break; }
    const int c     = r - chunk_ofs8(qb);
    const int q0    = qb * 128;
    const int tile0 = 8 * c;
    const int ntk   = min(8, 2 * (qb + 1) - 8 * c);
    const int slot  = bh * 40 + r;
    const unsigned short* Qb = Qg + (size_t)bh * 131072;
    const unsigned short* Kb = Kg + (size_t)bh * 131072;
    const unsigned short* Vb = Vg + (size_t)bh * 131072;
    const int qrow = q0 + wm + ql;       // this lane's global q row

    // Q B-frags: col = q = ql, k = 16*c4 + 8*hi + j
    short8 qf[4];
    {
        const unsigned short* qr = Qb + (size_t)qrow * 64 + hi * 8;
        #pragma unroll
        for (int c4 = 0; c4 < 4; ++c4)
            qf[c4] = *(const short8*)(qr + c4 * 16);
    }

    floatx16 o[2];
    #pragma unroll
    for (int db = 0; db < 2; ++db)
        #pragma unroll
        for (int e = 0; e < 16; ++e) o[db][e] = 0.f;
    float ls[4] = {0.f, 0.f, 0.f, 0.f};

    const int c0 = tid, c1 = tid + 256;
    uint4 vr0, vr1;

// K async stage: dest chunk c linear, source col = (c&7) ^ P(row), P = inverse
// of swzB's perm. Reads via swzB stay unchanged.
#define KSTAGE(BUF, TG)                                                        \
    {                                                                          \
        int base_ = (TG) * 64;                                                 \
        int r0_ = c0 >> 3, j0_ = (c0 & 7) ^ (r0_ & 7) ^ ((r0_ >> 2) & 6);      \
        int r1_ = c1 >> 3, j1_ = (c1 & 7) ^ (r1_ & 7) ^ ((r1_ >> 2) & 6);      \
        async_cp16(Kb + (size_t)(base_ + r0_) * 64 + (j0_ & 7) * 8,            \
                   &Ks[BUF][c0 * 8]);                                          \
        async_cp16(Kb + (size_t)(base_ + r1_) * 64 + (j1_ & 7) * 8,            \
                   &Ks[BUF][c1 * 8]);                                          \
    }
#define LOADV(TG)                                                              \
    {                                                                          \
        int base = (TG) * 64;                                                  \
        vr0 = *(const uint4*)(Vb + (size_t)(base + (c0 & 63)) * 64 + (c0 >> 6) * 8); \
        vr1 = *(const uint4*)(Vb + (size_t)(base + (c1 & 63)) * 64 + (c1 >> 6) * 8); \
    }
// Vt transposed write: logical (row=(c>>6)*8+i, kv=c&63), swzB element address
#define WRITEV(BUF)                                                            \
    {                                                                          \
        unsigned short t0[8]; *(uint4*)t0 = vr0;                               \
        _Pragma("unroll") for (int i_ = 0; i_ < 8; ++i_) {                     \
            int rv = (c0 >> 6) * 8 + i_;                                       \
            Vt[BUF][rv * 64 + (((((c0 >> 3) & 7) ^ i_ ^ ((rv >> 2) & 6)) & 7) << 3) + (c0 & 7)] = t0[i_]; \
        }                                                                      \
        unsigned short t1[8]; *(uint4*)t1 = vr1;                               \
        _Pragma("unroll") for (int i_ = 0; i_ < 8; ++i_) {                     \
            int rv = (c1 >> 6) * 8 + i_;                                       \
            Vt[BUF][rv * 64 + (((((c1 >> 3) & 7) ^ i_ ^ ((rv >> 2) & 6)) & 7) << 3) + (c1 & 7)] = t1[i_]; \
        }                                                                      \
    }

    KSTAGE(0, tile0);
    LOADV(tile0);
    WRITEV(0);
    __syncthreads();                 // drains K DMA (vmcnt0) + V writes

    for (int kt = 0; kt < ntk; ++kt) {
        const int  tg   = tile0 + kt;
        const int  cur  = kt & 1;
        const bool more = (kt + 1 < ntk);
        if (more) {
            KSTAGE(cur ^ 1, tg + 1);   // DMA into buffer freed by prev barrier
            LOADV(tg + 1);
        }

        #pragma unroll
        for (int bb = 0; bb < 2; ++bb) {
            // ---- QK^T (swapped): s^T[kv][q], A = K rows, B = Q cols ----
            short8 kf[4];
            #pragma unroll
            for (int c4 = 0; c4 < 4; ++c4)
                kf[c4] = *(const short8*)&Ks[cur][swzB(32 * bb + ql, 2 * c4 + hi)];
            floatx16 s;
            #pragma unroll
            for (int e = 0; e < 16; ++e) s[e] = -C2;   // fold softmax offset into C-in
            #pragma unroll
            for (int c4 = 0; c4 < 4; ++c4)
                s = __builtin_amdgcn_mfma_f32_32x32x16_bf16(kf[c4], qf[c4], s, 0, 0, 0);

            // ---- softmax: p = 2^s (s pre-offset by -C2); masked -> 0 ----
            const int  kvb = tg * 64 + 32 * bb + 4 * hi;
            const bool nm  = (tg * 64 + 32 * bb + 31) > (q0 + wm);
            if (nm) {
                #pragma unroll
                for (int e = 0; e < 16; ++e)
                    if (kvb + (e & 3) + 8 * (e >> 2) > qrow) s[e] = -1e30f;
            }
            float pv[16];
            #pragma unroll
            for (int e = 0; e < 16; ++e) {
                pv[e] = __builtin_amdgcn_exp2f(s[e]);
                ls[e & 3] += pv[e];
            }

            // ---- P -> bf16 A-frags in-register ----
            unsigned w[8];
            #pragma unroll
            for (int m = 0; m < 4; ++m) {
                w[2 * m]     = cvtpk(pv[4 * m],     pv[4 * m + 1]);
                w[2 * m + 1] = cvtpk(pv[4 * m + 2], pv[4 * m + 3]);
            }
            plswap(w[0], w[2]);   // frag g=0: words 0,2
            plswap(w[1], w[3]);   // frag g=0: words 1,3
            plswap(w[4], w[6]);   // frag g=1: words 0,2
            plswap(w[5], w[7]);   // frag g=1: words 1,3
            uint4v u0 = {w[0], w[1], w[2], w[3]};
            uint4v u1 = {w[4], w[5], w[6], w[7]};
            short8 pa0 = __builtin_bit_cast(short8, u0);
            short8 pa1 = __builtin_bit_cast(short8, u1);

            // ---- PV: A = P frags, B = V^T (col = d, k = kv) ----
            #pragma unroll
            for (int db = 0; db < 2; ++db) {
                short8 vf0 = *(const short8*)&Vt[cur][swzB(32 * db + ql, 4 * bb + hi)];
                short8 vf1 = *(const short8*)&Vt[cur][swzB(32 * db + ql, 4 * bb + 2 + hi)];
                o[db] = __builtin_amdgcn_mfma_f32_32x32x16_bf16(pa0, vf0, o[db], 0, 0, 0);
                o[db] = __builtin_amdgcn_mfma_f32_32x32x16_bf16(pa1, vf1, o[db], 0, 0, 0);
            }
        }

        if (more) {
            WRITEV(cur ^ 1);
            __syncthreads();          // drains K DMA + V writes; frees cur
        }
    }
#undef KSTAGE
#undef LOADV
#undef WRITEV

    float lsum = (ls[0] + ls[1]) + (ls[2] + ls[3]);
    lsum += __shfl_xor(lsum, 32);
    if (lane < 32)
        pL[(size_t)slot * 128 + wm + ql] = lsum;

    // ---- epilogue: restage o (bf16) in dead Ks LDS, then full-line stores ----
    __syncthreads();                       // all waves done reading Ks/Vt
    unsigned short* Ost = &Ks[0][0];       // 16KB: [128][64], chunk ^ (row&7)
    #pragma unroll
    for (int db = 0; db < 2; ++db)
        #pragma unroll
        for (int e = 0; e < 16; ++e) {
            int row = wm + (e & 3) + 8 * (e >> 2) + 4 * hi;
            int col = db * 32 + ql;
            Ost[row * 64 + ((((col >> 3) ^ (row & 7)) & 7) << 3) + (col & 7)] =
                f2b(o[db][e]);
        }
    __syncthreads();
    #pragma unroll
    for (int p = 0; p < 4; ++p) {
        int chunk = p * 256 + tid;         // 1024 chunks = 128 rows x 8
        int row = chunk >> 3, cc = chunk & 7;
        uint4 val = *(const uint4*)&Ost[row * 64 + (((cc ^ (row & 7)) & 7) << 3)];
        *(uint4*)(pO + ((size_t)slot * 128 + row) * 64 + cc * 8) = val;
    }
}

// ---------------- attention combine (fixed base: plain sums) ----------------
// grid (16, 24); merges <=4 chunks of 512 kv each.
__global__ __launch_bounds__(256) void attn_combine(const unsigned short* __restrict__ pO,
                                                    const float* __restrict__ pL,
                                                    unsigned short* __restrict__ ctx) {
    const int qb  = blockIdx.x;
    const int bh  = blockIdx.y;
    const int b   = bh / 12, h = bh % 12;
    const int nch = (qb >> 2) + 1;             // ceil((qb+1)/4)
    const int slot0 = bh * 40 + chunk_ofs8(qb);
    const int tid = threadIdx.x;
    const int row = tid >> 1;
    const int col0 = (tid & 1) * 32;

    float L = 0.f;
    for (int i = 0; i < nch; ++i)
        L += pL[(size_t)(slot0 + i) * 128 + row];

    float acc[32];
    #pragma unroll
    for (int j = 0; j < 32; ++j) acc[j] = 0.f;
    for (int i = 0; i < nch; ++i) {
        const unsigned short* p = pO + ((size_t)(slot0 + i) * 128 + row) * 64 + col0;
        #pragma unroll
        for (int v4 = 0; v4 < 4; ++v4) {
            uint4 u = *(const uint4*)(p + v4 * 8);
            unsigned short t[8]; *(uint4*)t = u;
            #pragma unroll
            for (int j = 0; j < 8; ++j) acc[v4 * 8 + j] += b2f(t[j]);
        }
    }
    float inv = 1.f / L;
    unsigned short* orow = ctx + ((size_t)(b * 2048 + qb * 128 + row)) * 768 + h * 64 + col0;
    #pragma unroll
    for (int v4 = 0; v4 < 4; ++v4) {
        unsigned short t[8];
        #pragma unroll
        for (int j = 0; j < 8; ++j) t[j] = f2b(acc[v4 * 8 + j] * inv);
        *(uint4*)(orow + v4 * 8) = *(uint4*)t;
    }
}

// ---------------- fused reduce + bias + residual + LayerNorm ----------------
// Partials: fp32 via Pf or bf16 via Pb (exactly one non-null when nsplit>0).
__global__ __launch_bounds__(256) void resid_ln2(const float* __restrict__ X,
                                                 const float* __restrict__ Pf,
                                                 const unsigned short* __restrict__ Pb,
                                                 int nsplit,
                                                 const float* __restrict__ bv,
                                                 const float* __restrict__ gain,
                                                 const float* __restrict__ beta,
                                                 float* __restrict__ outF,
                                                 unsigned short* __restrict__ outB) {
    const int row = blockIdx.x;
    const int t   = threadIdx.x;
    const size_t off = (size_t)row * 768;
    float v[3];
    #pragma unroll
    for (int i = 0; i < 3; i++) {
        size_t c = off + t + i * 256;
        float r = X[c] + bv[t + i * 256];
        if (Pf) {
            for (int p = 0; p < nsplit; ++p) r += Pf[(size_t)p * 3145728 + c];
        } else {
            for (int p = 0; p < nsplit; ++p) r += b2f(Pb[(size_t)p * 3145728 + c]);
        }
        v[i] = r;
    }
    float s  = v[0] + v[1] + v[2];
    float s2 = v[0] * v[0] + v[1] * v[1] + v[2] * v[2];
    #pragma unroll
    for (int o2 = 32; o2 > 0; o2 >>= 1) {
        s  += __shfl_down(s,  o2);
        s2 += __shfl_down(s2, o2);
    }
    __shared__ float rs[4], rq[4];
    if ((t & 63) == 0) { rs[t >> 6] = s; rq[t >> 6] = s2; }
    __syncthreads();
    float S    = rs[0] + rs[1] + rs[2] + rs[3];
    float S2   = rq[0] + rq[1] + rq[2] + rq[3];
    float mean = S * (1.0f / 768.0f);
    float var  = S2 * (1.0f / 768.0f) - mean * mean;
    float inv  = rsqrtf(var + 1e-5f);
    #pragma unroll
    for (int i = 0; i < 3; i++) {
        int c   = t + i * 256;
        float y = gain[c] * (v[i] - mean) * inv + beta[c];
        if (outF) outF[off + c] = y;
        if (outB) outB[off + c] = f2b(y);
    }
}

// ---------------------------------------------------------------------------
extern "C" void kernel_launch(void* const* d_in, const int* in_sizes, int n_in,
                              void* d_out, int out_size, void* d_ws, size_t ws_size,
                              hipStream_t stream) {
    const float* x    = (const float*)d_in[0];
    const float* Wqkv = (const float*)d_in[1];
    const float* Wout = (const float*)d_in[2];
    const float* bout = (const float*)d_in[3];
    const float* W1   = (const float*)d_in[4];
    const float* b1   = (const float*)d_in[5];
    const float* W2   = (const float*)d_in[6];
    const float* b2   = (const float*)d_in[7];
    const float* g1   = (const float*)d_in[8];
    const float* be1  = (const float*)d_in[9];
    const float* g2   = (const float*)d_in[10];
    const float* be2  = (const float*)d_in[11];
    float* out = (float*)d_out;

    // workspace layout (bytes), liveness-aliased; peak 83,361,792
    char* ws = (char*)d_ws;
    unsigned short* wqkvT  = (unsigned short*)(ws + 0);         // 3.5M  ->QKV
    unsigned short* woutT  = (unsigned short*)(ws + 3538944);   // 1.2M  ->Wout
    unsigned short* w1T    = (unsigned short*)(ws + 4718592);   // 4.7M  ->W1
    unsigned short* w2T    = (unsigned short*)(ws + 9437184);   // 4.7M  ->W2
    unsigned short* xb     = (unsigned short*)(ws + 14155776);  // 6.3M  ->QKV
    unsigned short* qkvG   = (unsigned short*)(ws + 20447232);  // 18.9M ->attn_part
    unsigned short* Qg     = qkvG;
    unsigned short* Kg     = qkvG + 3145728;
    unsigned short* Vg     = qkvG + 6291456;
    unsigned short* pO     = (unsigned short*)(ws + 39321600);  // 15.7M ->combine (960 slots)
    float*          pL     = (float*)(ws + 67633152);           // 0.49M ->combine
    unsigned short* ctxb   = (unsigned short*)(ws + 14155776);  // 6.3M  combine->Wout (xb dead)
    float*          WoutP  = (float*)(ws + 39321600);           // 2x12.6M Wout->LN1 (pO dead)
    float*          h      = (float*)(ws + 20447232);           // 12.6M LN1->LN2 (qkvG dead)
    unsigned short* hb     = (unsigned short*)(ws + 77070336);  // 6.3M  LN1->W1
    unsigned short* ffb    = (unsigned short*)(ws + 39321600);  // 25.2M W1->W2 (WoutP dead)
    unsigned short* W2Pb   = (unsigned short*)(ws + 64487424);  // 2x6.3M bf16 W2->LN2; ends 77,070,336

    // 1) fused prepass
    prep_all<<<9984, 256, 0, stream>>>(x, xb, Wqkv, wqkvT, Wout, woutT, W1, w1T, W2, w2T);
    // 2) QKV projection (256^2 8-phase) -> Q/K/V [bh][s][64] bf16 (Q pre-scaled)
    gemm256<<<dim3(9, 16), 512, 0, stream>>>(xb, wqkvT, nullptr, qkvG, 2304, 768, 0, 1);
    // 3) kv-split flash attention (512-wide chunks) + combine -> ctx bf16
    attn_part<<<dim3(40, 24), 256, 0, stream>>>(Qg, Kg, Vg, pO, pL);
    attn_combine<<<dim3(16, 24), 256, 0, stream>>>(pO, pL, ctxb);
    // 4) out projection, split-K=2 -> fp32 partials (768 blocks = 3/CU exact)
    gemm_n64<<<dim3(12, 32, 2), 256, 0, stream>>>(ctxb, woutT, WoutP, nullptr, 768, 384);
    // 5) h = LN(x + sum WoutP + bout) -> fp32 + bf16
    resid_ln2<<<4096, 256, 0, stream>>>(x, WoutP, nullptr, 2, bout, g1, be1, h, hb);
    // 6) ff = relu(h @ W1 + b1) (256^2 8-phase) -> bf16
    gemm256<<<dim3(12, 16), 512, 0, stream>>>(hb, w1T, b1, ffb, 3072, 768, 1, 0);
    // 7) ff2 = ff @ W2, split-K=2 -> bf16 partials (768 blocks = 3/CU exact)
    gemm_n64<<<dim3(12, 32, 2), 256, 0, stream>>>(ffb, w2T, nullptr, W2Pb, 3072, 1536);
    // 8) out = LN(h + sum W2Pb + b2) -> fp32
    resid_ln2<<<4096, 256, 0, stream>>>(h, nullptr, W2Pb, 2, b2, g2, be2, out, nullptr);
}